// Round 3
// baseline (26965.353 us; speedup 1.0000x reference)
//
#include <hip/hip_runtime.h>
#include <math.h>

#define T_STEPS 8192
#define I_DIM   64
#define H_DIM   2048
#define O_DIM   128
#define NBLK    256     // one block per CU; each owns 8 h-indices (32 gate rows)
#define NTHR    512     // 8 waves
#define NSLOT   4       // h slot ring depth
#define SLOT_W  4096    // padded slot words: 256 CUs x 16 words (64B line each)
#define NAN_BITS 0x7FC00000u

typedef float v4f __attribute__((ext_vector_type(4)));

// ws layout: uint Hbits[NSLOT][SLOT_W]; CU c owns words c*16..c*16+7 of each
// slot (h[8c..8c+7]); words c*16+8..c*16+15 are pad (stay NaN forever).
// 64B padding => every cache line has exactly ONE publisher: no partial-line
// assembly, one probe-invalidate event per line per step (round-0 packed two
// CUs' 32B chunks per 64B line -> half-ready lines cached stale cost extra
// sleep+refetch rounds on the poll path).
__device__ __forceinline__ float sigmoid_f(float x) {
    return 1.0f / (1.0f + __expf(-x));
}
__device__ __forceinline__ float tanh_fast(float x) {
    // 2*sigmoid(2x)-1; saturates correctly for |x| large
    return 2.0f / (1.0f + __expf(-2.0f * x)) - 1.0f;
}

// DPP-based wave64 sum — VALU pipe, NOT the LDS pipe. CTRL must be immediate.
template <int CTRL>
__device__ __forceinline__ float dpp_add(float v) {
    int s = __builtin_amdgcn_update_dpp(0, __builtin_bit_cast(int, v),
                                        CTRL, 0xF, 0xF, true);
    return v + __builtin_bit_cast(float, s);
}
// After the sequence, lane 63 holds the full 64-lane sum.
__device__ __forceinline__ float wave_sum64_lane63(float v) {
    v = dpp_add<0x111>(v);  // row_shr:1
    v = dpp_add<0x112>(v);  // row_shr:2
    v = dpp_add<0x114>(v);  // row_shr:4
    v = dpp_add<0x118>(v);  // row_shr:8   -> lane15 of each row16 = row-partial
    v = dpp_add<0x142>(v);  // row_bcast:15 -> lane31 = sum(0..31), l63 = sum(32..63)
    v = dpp_add<0x143>(v);  // row_bcast:31 -> lane63 = sum(0..63)
    return v;
}

__global__ void init_ws_kernel(unsigned int* Hbits) {
    int tid = blockIdx.x * blockDim.x + threadIdx.x;
    if (tid < NSLOT * SLOT_W) {
        // slot 0 data words = h_0 = 0.0f; everything else (incl. all pads and
        // slots 1..3) = NaN sentinel ("not ready")
        Hbits[tid] = (tid < SLOT_W && (tid & 15) < 8) ? 0u : NAN_BITS;
    }
}

// Persistent LSTM recurrence — proven round-0 fabric (19.16 ms) with two
// low-risk edits: (1) 64B single-publisher line padding (index remap ONLY —
// poll instruction pattern, sleep(2) cadence, both barriers, gbuf, replicated
// elementwise, and the single coalesced 32B publish/reset from wave 0 are all
// verbatim); (2) x-part dot computed pre-poll from per-lane direct 16B x
// loads (read-only, L1/L2-hit) — xbuf deleted, xp hides under the poll wait.
// Round-1 (hot-spin + LDS-gather publish) and round-2 (hand-asm sc1 16B poll)
// both regressed — the compiler-emitted 4B atomic poll is load-bearing.
// Wave w: gate q = w>>1, joff = (w&1)*4; rows = q*2048 + cu*8 + joff + i
// Dot k-mapping: lane l covers k = m*256 + l*4 + j -> one ds_read_b128 per m.
__global__ __launch_bounds__(NTHR, 2) void lstm_persistent(
    const float* __restrict__ x,     // [T, 64]
    const float* __restrict__ Wih,   // [8192, 64]
    const float* __restrict__ Whh,   // [8192, 2048]
    const float* __restrict__ bih,   // [8192]
    const float* __restrict__ bhh,   // [8192]
    unsigned int* __restrict__ Hbits)// [NSLOT][SLOT_W] in ws (float bits)
{
    const int cu   = blockIdx.x;
    const int tid  = threadIdx.x;
    const int w    = tid >> 6;
    const int lane = tid & 63;

    __shared__ float hbuf[H_DIM];   // 8 KB, layout hbuf[k] = h[k]
    __shared__ float gbuf[32];      // gbuf[g*8 + j] = pre-activation of gate g, h-sub j

    const int q    = w >> 1;
    const int joff = (w & 1) * 4;
    const int row0 = q * H_DIM + cu * 8 + joff;

    // ---- one-time: W_hh fragment into registers (unified VGPR/AGPR file) ----
    // wreg[i][m] = W[row0+i][m*256 + lane*4 .. +3]   (coalesced 16B loads)
    v4f wreg[4][8];
#pragma unroll
    for (int i = 0; i < 4; i++) {
        const float* p = Whh + (size_t)(row0 + i) * H_DIM + lane * 4;
#pragma unroll
        for (int m = 0; m < 8; m++)
            wreg[i][m] = *(const v4f*)(p + m * 256);
    }
    // x-part: lane handles row (row0 + (lane>>4)), k-range (lane&15)*4 .. +4
    float xw[4];
    {
        const int xr = row0 + (lane >> 4);
        const float* p = Wih + (size_t)xr * I_DIM + (lane & 15) * 4;
#pragma unroll
        for (int m = 0; m < 4; m++) xw[m] = p[m];
    }
    // biases: every wave keeps them (elementwise phase is replicated per wave)
    float bias[4] = {0.f, 0.f, 0.f, 0.f};
    if (lane < 8) {
#pragma unroll
        for (int g = 0; g < 4; g++) {
            int r = g * H_DIM + cu * 8 + lane;
            bias[g] = bih[r] + bhh[r];
        }
    }
    float cstate = 0.0f;   // replicated in lanes 0..7 of every wave

    // poll base for this thread: h[4*tid .. 4*tid+3] live in CU (tid>>1)'s
    // 64B line at word (tid>>1)*16 + (tid&1)*4  (4 contiguous words)
    const int poll_off = (tid >> 1) * 16 + (tid & 1) * 4;
    const int xb = (lane & 15) * 4;   // this lane's x k-range

    for (int t = 0; t < T_STEPS; t++) {
        const int slot_r = t & (NSLOT - 1);
        const int slot_w = (t + 1) & (NSLOT - 1);
        const int slot_z = (t + 2) & (NSLOT - 1);

        // ---- 0. x-part dot NOW (independent of h; hides under the poll) ----
        float xp = 0.f;
        {
            v4f xv = *(const v4f*)(x + (size_t)t * I_DIM + xb);
#pragma unroll
            for (int m = 0; m < 4; m++) xp += xw[m] * xv[m];
        }

        // ---- 1. poll h_t (data-as-flag) and stage into LDS ----
        // 4x 4B compiler-emitted atomic loads; s_sleep(2) on EVERY failed pass
        // (proven round-6 cadence). Do not hand-roll these loads (round 2).
        {
            const unsigned int* Hr = Hbits + slot_r * SLOT_W + poll_off;
            unsigned int u0, u1, u2, u3;
            for (;;) {
                u0 = __hip_atomic_load(Hr + 0, __ATOMIC_RELAXED, __HIP_MEMORY_SCOPE_AGENT);
                u1 = __hip_atomic_load(Hr + 1, __ATOMIC_RELAXED, __HIP_MEMORY_SCOPE_AGENT);
                u2 = __hip_atomic_load(Hr + 2, __ATOMIC_RELAXED, __HIP_MEMORY_SCOPE_AGENT);
                u3 = __hip_atomic_load(Hr + 3, __ATOMIC_RELAXED, __HIP_MEMORY_SCOPE_AGENT);
                bool miss = (u0 == NAN_BITS) | (u1 == NAN_BITS) |
                            (u2 == NAN_BITS) | (u3 == NAN_BITS);
                if (!miss) break;
                __builtin_amdgcn_s_sleep(2);
            }
            v4f hv4 = { __uint_as_float(u0), __uint_as_float(u1),
                        __uint_as_float(u2), __uint_as_float(u3) };
            *(v4f*)&hbuf[tid * 4] = hv4;   // hbuf[k] = h[k], one ds_write_b128
        }
        // reset own chunk 2 slots ahead (holds h_{t-2}, fully consumed, skew<=1).
        // Coalesced: 8 lanes of wave 0, one 32B transaction. Placement after
        // poll success is REQUIRED (ring-safety: resetting earlier can NaN a
        // chunk a straggler CU is still reading -> hang).
        if (w == 0 && lane < 8) {
            __hip_atomic_store(Hbits + slot_z * SLOT_W + cu * 16 + lane, NAN_BITS,
                               __ATOMIC_RELAXED, __HIP_MEMORY_SCOPE_AGENT);
        }
        __syncthreads();

        // ---- 2. dot products: 4 rows per wave, 8 x (ds_read_b128 + packed FMA) ----
        v4f av0 = {0.f,0.f,0.f,0.f}, av1 = {0.f,0.f,0.f,0.f};
        v4f av2 = {0.f,0.f,0.f,0.f}, av3 = {0.f,0.f,0.f,0.f};
#pragma unroll
        for (int m = 0; m < 8; m++) {
            v4f hv = *(const v4f*)&hbuf[m * 256 + lane * 4];
            av0 += wreg[0][m] * hv;
            av1 += wreg[1][m] * hv;
            av2 += wreg[2][m] * hv;
            av3 += wreg[3][m] * hv;
        }
        float acc0 = (av0[0] + av0[1]) + (av0[2] + av0[3]);
        float acc1 = (av1[0] + av1[1]) + (av1[2] + av1[3]);
        float acc2 = (av2[0] + av2[1]) + (av2[2] + av2[3]);
        float acc3 = (av3[0] + av3[1]) + (av3[2] + av3[3]);
        {   // fold in W_ih * x_t (xp precomputed before the poll)
            const int sel = lane >> 4;
            acc0 += (sel == 0) ? xp : 0.0f;
            acc1 += (sel == 1) ? xp : 0.0f;
            acc2 += (sel == 2) ? xp : 0.0f;
            acc3 += (sel == 3) ? xp : 0.0f;
        }
        // ---- 3. DPP reduction (VALU pipe); totals land in lane 63 ----
        acc0 = wave_sum64_lane63(acc0);
        acc1 = wave_sum64_lane63(acc1);
        acc2 = wave_sum64_lane63(acc2);
        acc3 = wave_sum64_lane63(acc3);
        if (lane == 63) {
            gbuf[q * 8 + joff + 0] = acc0;
            gbuf[q * 8 + joff + 1] = acc1;
            gbuf[q * 8 + joff + 2] = acc2;
            gbuf[q * 8 + joff + 3] = acc3;
        }
        __syncthreads();

        // ---- 4. elementwise cell update, replicated in every wave (lanes 0..7);
        //         wave 0 publishes — ONE coalesced 32B store = the ready flag ----
        if (lane < 8) {
            float gi = gbuf[0 * 8 + lane] + bias[0];
            float gf = gbuf[1 * 8 + lane] + bias[1];
            float gg = gbuf[2 * 8 + lane] + bias[2];
            float go = gbuf[3 * 8 + lane] + bias[3];
            float iv = sigmoid_f(gi);
            float fv = sigmoid_f(gf);
            float gv = tanh_fast(gg);
            float ov = sigmoid_f(go);
            cstate = fv * cstate + iv * gv;
            float hval = ov * tanh_fast(cstate);
            if (w == 0) {
                __hip_atomic_store(Hbits + slot_w * SLOT_W + cu * 16 + lane,
                                   __float_as_uint(hval),
                                   __ATOMIC_RELAXED, __HIP_MEMORY_SCOPE_AGENT);
            }
        }
        // next iteration's poll phase touches only Hbits/hbuf; gbuf reuse is
        // protected by the next iteration's first __syncthreads.
    }
}

// Final linear: out[o] = h_T . W_lin[o,:] + b_lin[o].  One wave per output.
// h_T lives in slot (T & 3) == 0, padded layout: h[k] at word (k>>3)*16+(k&7).
__global__ void final_linear(const unsigned int* __restrict__ hTbits,
                             const float* __restrict__ Wlin,
                             const float* __restrict__ blin,
                             float* __restrict__ out)
{
    int gw   = (blockIdx.x * blockDim.x + threadIdx.x) >> 6;
    int lane = threadIdx.x & 63;
    if (gw < O_DIM) {
        const float* wp = Wlin + (size_t)gw * H_DIM;
        float s = 0.f;
        for (int k = lane; k < H_DIM; k += 64) {
            float hv = __uint_as_float(hTbits[(k >> 3) * 16 + (k & 7)]);
            s += wp[k] * hv;
        }
#pragma unroll
        for (int off = 32; off; off >>= 1) s += __shfl_xor(s, off, 64);
        if (lane == 0) out[gw] = s + blin[gw];
    }
}

extern "C" void kernel_launch(void* const* d_in, const int* in_sizes, int n_in,
                              void* d_out, int out_size, void* d_ws, size_t ws_size,
                              hipStream_t stream)
{
    const float* x    = (const float*)d_in[0];
    const float* Wih  = (const float*)d_in[1];
    const float* Whh  = (const float*)d_in[2];
    const float* bih  = (const float*)d_in[3];
    const float* bhh  = (const float*)d_in[4];
    const float* Wlin = (const float*)d_in[5];
    const float* blin = (const float*)d_in[6];
    float* out = (float*)d_out;

    unsigned int* Hbits = (unsigned int*)d_ws;

    hipLaunchKernelGGL(init_ws_kernel, dim3((NSLOT * SLOT_W + 255) / 256), dim3(256),
                       0, stream, Hbits);

    void* args[] = { (void*)&x, (void*)&Wih, (void*)&Whh, (void*)&bih, (void*)&bhh,
                     (void*)&Hbits };
    (void)hipLaunchCooperativeKernel(reinterpret_cast<void*>(lstm_persistent),
                                     dim3(NBLK), dim3(NTHR), args, 0, stream);

    // h_T is in slot (T_STEPS & 3) == 0
    hipLaunchKernelGGL(final_linear, dim3(32), dim3(256), 0, stream,
                       (const unsigned int*)Hbits, Wlin, blin, out);
}

// Round 4
// 18456.873 us; speedup vs baseline: 1.4610x; 1.4610x over previous
//
#include <hip/hip_runtime.h>
#include <math.h>

#define T_STEPS 8192
#define I_DIM   64
#define H_DIM   2048
#define O_DIM   128
#define NBLK    256     // one block per CU; each owns 8 h-indices (32 gate rows)
#define NTHR    512     // 8 waves
#define NSLOT   4       // h slot ring depth
#define NAN_BITS 0x7FC00000u

typedef float v4f __attribute__((ext_vector_type(4)));

// ws layout: float Hbuf[NSLOT][2048]  (packed — round-3's 64B padding DOUBLED
// per-step line footprint and FETCH; reverted)
__device__ __forceinline__ float sigmoid_f(float x) {
    return 1.0f / (1.0f + __expf(-x));
}
__device__ __forceinline__ float tanh_fast(float x) {
    // 2*sigmoid(2x)-1; saturates correctly for |x| large
    return 2.0f / (1.0f + __expf(-2.0f * x)) - 1.0f;
}

// DPP-based wave64 sum — VALU pipe, NOT the LDS pipe (__shfl_xor = ds_bpermute
// burns ~1150 cy/step/CU of LDS throughput at 8 waves; DPP adds are VALU).
// CTRL must be an immediate -> template parameter.
template <int CTRL>
__device__ __forceinline__ float dpp_add(float v) {
    int s = __builtin_amdgcn_update_dpp(0, __builtin_bit_cast(int, v),
                                        CTRL, 0xF, 0xF, true);
    return v + __builtin_bit_cast(float, s);
}
// After the sequence, lane 63 holds the full 64-lane sum.
__device__ __forceinline__ float wave_sum64_lane63(float v) {
    v = dpp_add<0x111>(v);  // row_shr:1
    v = dpp_add<0x112>(v);  // row_shr:2
    v = dpp_add<0x114>(v);  // row_shr:4
    v = dpp_add<0x118>(v);  // row_shr:8   -> lane15 of each row16 = row-partial
    v = dpp_add<0x142>(v);  // row_bcast:15 -> lane31 = sum(0..31), l63 = sum(32..63)
    v = dpp_add<0x143>(v);  // row_bcast:31 -> lane63 = sum(0..63)
    return v;
}

__global__ void init_ws_kernel(unsigned int* Hbits) {
    int tid = blockIdx.x * blockDim.x + threadIdx.x;
    if (tid < NSLOT * H_DIM) {
        // slot 0 = h_0 = 0.0f; slots 1..3 = NaN sentinel ("not ready")
        Hbits[tid] = (tid < H_DIM) ? 0u : NAN_BITS;
    }
}

// Persistent LSTM recurrence — the proven 19.16 ms round-0 fabric, VERBATIM,
// with exactly ONE token changed: s_sleep(2) -> s_sleep(1) (finer detection
// sampling on the straggler tail; backoff still on EVERY failed pass — this
// is NOT the round-1 hot-spin, which collapsed).
// Deviation ledger (all measured worse): hot-spin/predicated poll +20% and
// congestion collapse; hand-asm sc1 16B poll +16% (compiler-emitted 4B atomic
// poll is load-bearing); 64B single-publisher padding +41% (FETCH scales with
// slot line count). WRITE_SIZE==8192*256*64B proves publishes already write
// through L2 per step — store-side cache tricks attack a non-cost.
// Wave w: gate q = w>>1, joff = (w&1)*4; rows = q*2048 + cu*8 + joff + i
// Dot k-mapping: lane l covers k = m*256 + l*4 + j -> one ds_read_b128 per m.
__global__ __launch_bounds__(NTHR, 2) void lstm_persistent(
    const float* __restrict__ x,     // [T, 64]
    const float* __restrict__ Wih,   // [8192, 64]
    const float* __restrict__ Whh,   // [8192, 2048]
    const float* __restrict__ bih,   // [8192]
    const float* __restrict__ bhh,   // [8192]
    unsigned int* __restrict__ Hbits)// [NSLOT][2048] in ws (float bits)
{
    const int cu   = blockIdx.x;
    const int tid  = threadIdx.x;
    const int w    = tid >> 6;
    const int lane = tid & 63;

    __shared__ float hbuf[H_DIM];   // 8 KB, layout hbuf[k] = h[k]
    __shared__ float xbuf[I_DIM];
    __shared__ float gbuf[32];      // gbuf[g*8 + j] = pre-activation of gate g, h-sub j

    const int q    = w >> 1;
    const int joff = (w & 1) * 4;
    const int row0 = q * H_DIM + cu * 8 + joff;

    // ---- one-time: W_hh fragment into registers (unified VGPR/AGPR file) ----
    // wreg[i][m] = W[row0+i][m*256 + lane*4 .. +3]   (coalesced 16B loads)
    v4f wreg[4][8];
#pragma unroll
    for (int i = 0; i < 4; i++) {
        const float* p = Whh + (size_t)(row0 + i) * H_DIM + lane * 4;
#pragma unroll
        for (int m = 0; m < 8; m++)
            wreg[i][m] = *(const v4f*)(p + m * 256);
    }
    // x-part: lane handles row (row0 + (lane>>4)), k-range (lane&15)*4 .. +4
    float xw[4];
    {
        const int xr = row0 + (lane >> 4);
        const float* p = Wih + (size_t)xr * I_DIM + (lane & 15) * 4;
#pragma unroll
        for (int m = 0; m < 4; m++) xw[m] = p[m];
    }
    // biases: every wave keeps them (elementwise phase is replicated per wave)
    float bias[4] = {0.f, 0.f, 0.f, 0.f};
    if (lane < 8) {
#pragma unroll
        for (int g = 0; g < 4; g++) {
            int r = g * H_DIM + cu * 8 + lane;
            bias[g] = bih[r] + bhh[r];
        }
    }
    float cstate = 0.0f;   // replicated in lanes 0..7 of every wave

    for (int t = 0; t < T_STEPS; t++) {
        const int slot_r = t & (NSLOT - 1);
        const int slot_w = (t + 1) & (NSLOT - 1);
        const int slot_z = (t + 2) & (NSLOT - 1);

        // hoist the independent x load above the spin
        float xv_own = (tid < I_DIM) ? x[(size_t)t * I_DIM + tid] : 0.0f;

        // ---- 1. poll h_t (data-as-flag) and stage into LDS ----
        // s_sleep(1) backoff on failed passes (ONLY change vs round-0's
        // sleep(2): halves the sampling quantum on the straggler tail).
        {
            const unsigned int* Hr = Hbits + slot_r * H_DIM;
            unsigned int u0, u1, u2, u3;
            for (;;) {
                u0 = __hip_atomic_load(Hr + tid,             __ATOMIC_RELAXED, __HIP_MEMORY_SCOPE_AGENT);
                u1 = __hip_atomic_load(Hr + tid + 1 * NTHR,  __ATOMIC_RELAXED, __HIP_MEMORY_SCOPE_AGENT);
                u2 = __hip_atomic_load(Hr + tid + 2 * NTHR,  __ATOMIC_RELAXED, __HIP_MEMORY_SCOPE_AGENT);
                u3 = __hip_atomic_load(Hr + tid + 3 * NTHR,  __ATOMIC_RELAXED, __HIP_MEMORY_SCOPE_AGENT);
                bool miss = (u0 == NAN_BITS) | (u1 == NAN_BITS) |
                            (u2 == NAN_BITS) | (u3 == NAN_BITS);
                if (!miss) break;
                __builtin_amdgcn_s_sleep(1);
            }
            hbuf[tid]            = __uint_as_float(u0);
            hbuf[tid + 1 * NTHR] = __uint_as_float(u1);
            hbuf[tid + 2 * NTHR] = __uint_as_float(u2);
            hbuf[tid + 3 * NTHR] = __uint_as_float(u3);
            if (tid < I_DIM) xbuf[tid] = xv_own;
        }
        // reset own chunk 2 slots ahead (holds h_{t-2}, fully consumed, skew<=1).
        // Coalesced: 8 lanes of wave 0, one 32B transaction.
        if (w == 0 && lane < 8) {
            __hip_atomic_store(Hbits + slot_z * H_DIM + cu * 8 + lane, NAN_BITS,
                               __ATOMIC_RELAXED, __HIP_MEMORY_SCOPE_AGENT);
        }
        __syncthreads();

        // ---- 2. dot products: 4 rows per wave, 8 x (ds_read_b128 + packed FMA) ----
        v4f av0 = {0.f,0.f,0.f,0.f}, av1 = {0.f,0.f,0.f,0.f};
        v4f av2 = {0.f,0.f,0.f,0.f}, av3 = {0.f,0.f,0.f,0.f};
#pragma unroll
        for (int m = 0; m < 8; m++) {
            v4f hv = *(const v4f*)&hbuf[m * 256 + lane * 4];
            av0 += wreg[0][m] * hv;
            av1 += wreg[1][m] * hv;
            av2 += wreg[2][m] * hv;
            av3 += wreg[3][m] * hv;
        }
        float acc0 = (av0[0] + av0[1]) + (av0[2] + av0[3]);
        float acc1 = (av1[0] + av1[1]) + (av1[2] + av1[3]);
        float acc2 = (av2[0] + av2[1]) + (av2[2] + av2[3]);
        float acc3 = (av3[0] + av3[1]) + (av3[2] + av3[3]);
        {   // fold in W_ih * x_t
            float xp = 0.f;
            const int b = (lane & 15) * 4;
#pragma unroll
            for (int m = 0; m < 4; m++) xp += xw[m] * xbuf[b + m];
            const int sel = lane >> 4;
            acc0 += (sel == 0) ? xp : 0.0f;
            acc1 += (sel == 1) ? xp : 0.0f;
            acc2 += (sel == 2) ? xp : 0.0f;
            acc3 += (sel == 3) ? xp : 0.0f;
        }
        // ---- 3. DPP reduction (VALU pipe); totals land in lane 63 ----
        acc0 = wave_sum64_lane63(acc0);
        acc1 = wave_sum64_lane63(acc1);
        acc2 = wave_sum64_lane63(acc2);
        acc3 = wave_sum64_lane63(acc3);
        if (lane == 63) {
            gbuf[q * 8 + joff + 0] = acc0;
            gbuf[q * 8 + joff + 1] = acc1;
            gbuf[q * 8 + joff + 2] = acc2;
            gbuf[q * 8 + joff + 3] = acc3;
        }
        __syncthreads();

        // ---- 4. elementwise cell update, replicated in every wave (lanes 0..7);
        //         wave 0 publishes — ONE coalesced 32B store = the ready flag ----
        if (lane < 8) {
            float gi = gbuf[0 * 8 + lane] + bias[0];
            float gf = gbuf[1 * 8 + lane] + bias[1];
            float gg = gbuf[2 * 8 + lane] + bias[2];
            float go = gbuf[3 * 8 + lane] + bias[3];
            float iv = sigmoid_f(gi);
            float fv = sigmoid_f(gf);
            float gv = tanh_fast(gg);
            float ov = sigmoid_f(go);
            cstate = fv * cstate + iv * gv;
            float hval = ov * tanh_fast(cstate);
            if (w == 0) {
                __hip_atomic_store(Hbits + slot_w * H_DIM + cu * 8 + lane,
                                   __float_as_uint(hval),
                                   __ATOMIC_RELAXED, __HIP_MEMORY_SCOPE_AGENT);
            }
        }
        // next iteration's poll phase touches only Hbits/hbuf/xbuf; gbuf reuse
        // is protected by the next iteration's first __syncthreads.
    }
}

// Final linear: out[o] = h_T . W_lin[o,:] + b_lin[o].  One wave per output.
// h_T lives in slot (T & 3) == 0.
__global__ void final_linear(const float* __restrict__ hT,
                             const float* __restrict__ Wlin,
                             const float* __restrict__ blin,
                             float* __restrict__ out)
{
    int gw   = (blockIdx.x * blockDim.x + threadIdx.x) >> 6;
    int lane = threadIdx.x & 63;
    if (gw < O_DIM) {
        const float* wp = Wlin + (size_t)gw * H_DIM;
        float s = 0.f;
        for (int k = lane; k < H_DIM; k += 64)
            s += wp[k] * hT[k];
#pragma unroll
        for (int off = 32; off; off >>= 1) s += __shfl_xor(s, off, 64);
        if (lane == 0) out[gw] = s + blin[gw];
    }
}

extern "C" void kernel_launch(void* const* d_in, const int* in_sizes, int n_in,
                              void* d_out, int out_size, void* d_ws, size_t ws_size,
                              hipStream_t stream)
{
    const float* x    = (const float*)d_in[0];
    const float* Wih  = (const float*)d_in[1];
    const float* Whh  = (const float*)d_in[2];
    const float* bih  = (const float*)d_in[3];
    const float* bhh  = (const float*)d_in[4];
    const float* Wlin = (const float*)d_in[5];
    const float* blin = (const float*)d_in[6];
    float* out = (float*)d_out;

    unsigned int* Hbits = (unsigned int*)d_ws;

    hipLaunchKernelGGL(init_ws_kernel, dim3((NSLOT * H_DIM + 255) / 256), dim3(256),
                       0, stream, Hbits);

    void* args[] = { (void*)&x, (void*)&Wih, (void*)&Whh, (void*)&bih, (void*)&bhh,
                     (void*)&Hbits };
    (void)hipLaunchCooperativeKernel(reinterpret_cast<void*>(lstm_persistent),
                                     dim3(NBLK), dim3(NTHR), args, 0, stream);

    // h_T is in slot (T_STEPS & 3) == 0
    hipLaunchKernelGGL(final_linear, dim3(32), dim3(256), 0, stream,
                       (const float*)Hbits, Wlin, blin, out);
}

// Round 5
// 17630.362 us; speedup vs baseline: 1.5295x; 1.0469x over previous
//
#include <hip/hip_runtime.h>
#include <math.h>

#define T_STEPS 8192
#define I_DIM   64
#define H_DIM   2048
#define O_DIM   128
#define NBLK    256     // one block per CU; each owns 8 h-indices (32 gate rows)
#define NTHR    512     // 8 waves
#define NSLOT   4       // h slot ring depth
#define REPL    8       // one h replica per XCD
#define SLOT_W  (REPL * H_DIM)   // 16384 words per slot (8 replicas x 8KB)
#define NAN_BITS 0x7FC00000u

typedef float v4f __attribute__((ext_vector_type(4)));

// ws layout: uint Hbits[NSLOT][REPL][2048] (256 KB). Replica r of a slot is a
// full h image consumed ONLY by CUs on XCD r -> every 64B line has exactly one
// publisher and one consumer-XCD: probe fan-out 1, no 8-XCD concurrent refetch
// of the same hot line (the round-0..4 single-copy layout had all 8 XCDs
// refetching each freshly published line simultaneously).
__device__ __forceinline__ float sigmoid_f(float x) {
    return 1.0f / (1.0f + __expf(-x));
}
__device__ __forceinline__ float tanh_fast(float x) {
    // 2*sigmoid(2x)-1; saturates correctly for |x| large
    return 2.0f / (1.0f + __expf(-2.0f * x)) - 1.0f;
}

// DPP-based wave64 sum — VALU pipe, NOT the LDS pipe. CTRL must be immediate.
template <int CTRL>
__device__ __forceinline__ float dpp_add(float v) {
    int s = __builtin_amdgcn_update_dpp(0, __builtin_bit_cast(int, v),
                                        CTRL, 0xF, 0xF, true);
    return v + __builtin_bit_cast(float, s);
}
// After the sequence, lane 63 holds the full 64-lane sum.
__device__ __forceinline__ float wave_sum64_lane63(float v) {
    v = dpp_add<0x111>(v);  // row_shr:1
    v = dpp_add<0x112>(v);  // row_shr:2
    v = dpp_add<0x114>(v);  // row_shr:4
    v = dpp_add<0x118>(v);  // row_shr:8   -> lane15 of each row16 = row-partial
    v = dpp_add<0x142>(v);  // row_bcast:15 -> lane31 = sum(0..31), l63 = sum(32..63)
    v = dpp_add<0x143>(v);  // row_bcast:31 -> lane63 = sum(0..63)
    return v;
}

__global__ void init_ws_kernel(unsigned int* Hbits) {
    int tid = blockIdx.x * blockDim.x + threadIdx.x;
    if (tid < NSLOT * SLOT_W) {
        // slot 0 (all 8 replicas) = h_0 = 0.0f; slots 1..3 = NaN sentinel
        Hbits[tid] = (tid < SLOT_W) ? 0u : NAN_BITS;
    }
}

// Persistent LSTM recurrence — round-4 fabric (18.46 ms: round-0 + sleep(1))
// with ONE structural change: XCD-local replica publish/poll.
//  publish: wave 0, all 64 lanes, ONE store instruction; lane l -> replica
//           (l>>3), word cu*8+(l&7). Each replica line receives one contiguous
//           32B from one wave, once per step — byte-identical per line to the
//           proven single-copy publish (NOT the 8-stores-to-one-line scatter
//           that regressed in the earlier session).
//  poll:    each CU polls replica XCC_ID&7 (s_getreg, HW-verified). Value is
//           locality-only — ANY 0..7 is correct since all replicas are written.
// Deviation ledger (all measured worse): hot-spin/predicated poll +20% and
// collapse; hand-asm sc1 16B poll +16%; 64B per-CU line padding +41%.
// sleep(2)->sleep(1) measured -3.7% (straggler-max amplification confirmed).
// Wave w: gate q = w>>1, joff = (w&1)*4; rows = q*2048 + cu*8 + joff + i
// Dot k-mapping: lane l covers k = m*256 + l*4 + j -> one ds_read_b128 per m.
__global__ __launch_bounds__(NTHR, 2) void lstm_persistent(
    const float* __restrict__ x,     // [T, 64]
    const float* __restrict__ Wih,   // [8192, 64]
    const float* __restrict__ Whh,   // [8192, 2048]
    const float* __restrict__ bih,   // [8192]
    const float* __restrict__ bhh,   // [8192]
    unsigned int* __restrict__ Hbits)// [NSLOT][REPL][2048] in ws (float bits)
{
    const int cu   = blockIdx.x;
    const int tid  = threadIdx.x;
    const int w    = tid >> 6;
    const int lane = tid & 63;

    __shared__ float hbuf[H_DIM];   // 8 KB, layout hbuf[k] = h[k]
    __shared__ float xbuf[I_DIM];
    __shared__ float gbuf[32];      // gbuf[g*8 + j] = pre-activation of gate g, h-sub j

    const int q    = w >> 1;
    const int joff = (w & 1) * 4;
    const int row0 = q * H_DIM + cu * 8 + joff;

    // which XCD am I on? (stable for a persistent block; locality-only)
    unsigned int xcc;
    asm volatile("s_getreg_b32 %0, hwreg(HW_REG_XCC_ID)" : "=s"(xcc));
    const int myrep = (int)(xcc & 7u);

    // ---- one-time: W_hh fragment into registers (unified VGPR/AGPR file) ----
    // wreg[i][m] = W[row0+i][m*256 + lane*4 .. +3]   (coalesced 16B loads)
    v4f wreg[4][8];
#pragma unroll
    for (int i = 0; i < 4; i++) {
        const float* p = Whh + (size_t)(row0 + i) * H_DIM + lane * 4;
#pragma unroll
        for (int m = 0; m < 8; m++)
            wreg[i][m] = *(const v4f*)(p + m * 256);
    }
    // x-part: lane handles row (row0 + (lane>>4)), k-range (lane&15)*4 .. +4
    float xw[4];
    {
        const int xr = row0 + (lane >> 4);
        const float* p = Wih + (size_t)xr * I_DIM + (lane & 15) * 4;
#pragma unroll
        for (int m = 0; m < 4; m++) xw[m] = p[m];
    }
    // biases: ALL lanes keep them for h-index (lane&7) — elementwise phase is
    // replicated per 8-lane group so wave 0's 64 lanes can publish 8 replicas.
    float bias[4];
#pragma unroll
    for (int g = 0; g < 4; g++) {
        int r = g * H_DIM + cu * 8 + (lane & 7);
        bias[g] = bih[r] + bhh[r];
    }
    float cstate = 0.0f;   // replicated: each lane tracks c for h-index (lane&7)

    for (int t = 0; t < T_STEPS; t++) {
        const int slot_r = t & (NSLOT - 1);
        const int slot_w = (t + 1) & (NSLOT - 1);
        const int slot_z = (t + 2) & (NSLOT - 1);

        // hoist the independent x load above the spin
        float xv_own = (tid < I_DIM) ? x[(size_t)t * I_DIM + tid] : 0.0f;

        // ---- 1. poll h_t from MY XCD's replica (data-as-flag), stage to LDS ----
        // 4x 4B compiler-emitted atomic loads (do not hand-roll — round 2);
        // s_sleep(1) on EVERY failed pass (round-4 proven cadence).
        {
            const unsigned int* Hr = Hbits + slot_r * SLOT_W + myrep * H_DIM;
            unsigned int u0, u1, u2, u3;
            for (;;) {
                u0 = __hip_atomic_load(Hr + tid,             __ATOMIC_RELAXED, __HIP_MEMORY_SCOPE_AGENT);
                u1 = __hip_atomic_load(Hr + tid + 1 * NTHR,  __ATOMIC_RELAXED, __HIP_MEMORY_SCOPE_AGENT);
                u2 = __hip_atomic_load(Hr + tid + 2 * NTHR,  __ATOMIC_RELAXED, __HIP_MEMORY_SCOPE_AGENT);
                u3 = __hip_atomic_load(Hr + tid + 3 * NTHR,  __ATOMIC_RELAXED, __HIP_MEMORY_SCOPE_AGENT);
                bool miss = (u0 == NAN_BITS) | (u1 == NAN_BITS) |
                            (u2 == NAN_BITS) | (u3 == NAN_BITS);
                if (!miss) break;
                __builtin_amdgcn_s_sleep(1);
            }
            hbuf[tid]            = __uint_as_float(u0);
            hbuf[tid + 1 * NTHR] = __uint_as_float(u1);
            hbuf[tid + 2 * NTHR] = __uint_as_float(u2);
            hbuf[tid + 3 * NTHR] = __uint_as_float(u3);
            if (tid < I_DIM) xbuf[tid] = xv_own;
        }
        // reset own chunk in ALL replicas 2 slots ahead (holds h_{t-2}, fully
        // consumed; ring-safety unchanged — poll success at t implies no CU is
        // still reading slot (t+2)&3). One 64-lane store, 8x32B transactions.
        if (w == 0) {
            __hip_atomic_store(Hbits + slot_z * SLOT_W + (lane >> 3) * H_DIM
                                   + cu * 8 + (lane & 7), NAN_BITS,
                               __ATOMIC_RELAXED, __HIP_MEMORY_SCOPE_AGENT);
        }
        __syncthreads();

        // ---- 2. dot products: 4 rows per wave, 8 x (ds_read_b128 + packed FMA) ----
        v4f av0 = {0.f,0.f,0.f,0.f}, av1 = {0.f,0.f,0.f,0.f};
        v4f av2 = {0.f,0.f,0.f,0.f}, av3 = {0.f,0.f,0.f,0.f};
#pragma unroll
        for (int m = 0; m < 8; m++) {
            v4f hv = *(const v4f*)&hbuf[m * 256 + lane * 4];
            av0 += wreg[0][m] * hv;
            av1 += wreg[1][m] * hv;
            av2 += wreg[2][m] * hv;
            av3 += wreg[3][m] * hv;
        }
        float acc0 = (av0[0] + av0[1]) + (av0[2] + av0[3]);
        float acc1 = (av1[0] + av1[1]) + (av1[2] + av1[3]);
        float acc2 = (av2[0] + av2[1]) + (av2[2] + av2[3]);
        float acc3 = (av3[0] + av3[1]) + (av3[2] + av3[3]);
        {   // fold in W_ih * x_t
            float xp = 0.f;
            const int b = (lane & 15) * 4;
#pragma unroll
            for (int m = 0; m < 4; m++) xp += xw[m] * xbuf[b + m];
            const int sel = lane >> 4;
            acc0 += (sel == 0) ? xp : 0.0f;
            acc1 += (sel == 1) ? xp : 0.0f;
            acc2 += (sel == 2) ? xp : 0.0f;
            acc3 += (sel == 3) ? xp : 0.0f;
        }
        // ---- 3. DPP reduction (VALU pipe); totals land in lane 63 ----
        acc0 = wave_sum64_lane63(acc0);
        acc1 = wave_sum64_lane63(acc1);
        acc2 = wave_sum64_lane63(acc2);
        acc3 = wave_sum64_lane63(acc3);
        if (lane == 63) {
            gbuf[q * 8 + joff + 0] = acc0;
            gbuf[q * 8 + joff + 1] = acc1;
            gbuf[q * 8 + joff + 2] = acc2;
            gbuf[q * 8 + joff + 3] = acc3;
        }
        __syncthreads();

        // ---- 4. elementwise cell update, replicated per 8-lane group (all
        //         waves, for cstate continuity); wave 0 publishes ALL 8
        //         replicas with ONE 64-lane store instruction ----
        {
            const int j = lane & 7;
            float gi = gbuf[0 * 8 + j] + bias[0];
            float gf = gbuf[1 * 8 + j] + bias[1];
            float gg = gbuf[2 * 8 + j] + bias[2];
            float go = gbuf[3 * 8 + j] + bias[3];
            float iv = sigmoid_f(gi);
            float fv = sigmoid_f(gf);
            float gv = tanh_fast(gg);
            float ov = sigmoid_f(go);
            cstate = fv * cstate + iv * gv;
            float hval = ov * tanh_fast(cstate);
            if (w == 0) {
                __hip_atomic_store(Hbits + slot_w * SLOT_W + (lane >> 3) * H_DIM
                                       + cu * 8 + j,
                                   __float_as_uint(hval),
                                   __ATOMIC_RELAXED, __HIP_MEMORY_SCOPE_AGENT);
            }
        }
        // next iteration's poll phase touches only Hbits/hbuf/xbuf; gbuf reuse
        // is protected by the next iteration's first __syncthreads.
    }
}

// Final linear: out[o] = h_T . W_lin[o,:] + b_lin[o].  One wave per output.
// h_T lives in slot (T & 3) == 0, replica 0 (== base of Hbits).
__global__ void final_linear(const float* __restrict__ hT,
                             const float* __restrict__ Wlin,
                             const float* __restrict__ blin,
                             float* __restrict__ out)
{
    int gw   = (blockIdx.x * blockDim.x + threadIdx.x) >> 6;
    int lane = threadIdx.x & 63;
    if (gw < O_DIM) {
        const float* wp = Wlin + (size_t)gw * H_DIM;
        float s = 0.f;
        for (int k = lane; k < H_DIM; k += 64)
            s += wp[k] * hT[k];
#pragma unroll
        for (int off = 32; off; off >>= 1) s += __shfl_xor(s, off, 64);
        if (lane == 0) out[gw] = s + blin[gw];
    }
}

extern "C" void kernel_launch(void* const* d_in, const int* in_sizes, int n_in,
                              void* d_out, int out_size, void* d_ws, size_t ws_size,
                              hipStream_t stream)
{
    const float* x    = (const float*)d_in[0];
    const float* Wih  = (const float*)d_in[1];
    const float* Whh  = (const float*)d_in[2];
    const float* bih  = (const float*)d_in[3];
    const float* bhh  = (const float*)d_in[4];
    const float* Wlin = (const float*)d_in[5];
    const float* blin = (const float*)d_in[6];
    float* out = (float*)d_out;

    unsigned int* Hbits = (unsigned int*)d_ws;

    hipLaunchKernelGGL(init_ws_kernel, dim3((NSLOT * SLOT_W + 255) / 256), dim3(256),
                       0, stream, Hbits);

    void* args[] = { (void*)&x, (void*)&Wih, (void*)&Whh, (void*)&bih, (void*)&bhh,
                     (void*)&Hbits };
    (void)hipLaunchCooperativeKernel(reinterpret_cast<void*>(lstm_persistent),
                                     dim3(NBLK), dim3(NTHR), args, 0, stream);

    // h_T is in slot (T_STEPS & 3) == 0, replica 0
    hipLaunchKernelGGL(final_linear, dim3(32), dim3(256), 0, stream,
                       (const float*)Hbits, Wlin, blin, out);
}